// Round 5
// baseline (966.667 us; speedup 1.0000x reference)
//
#include <hip/hip_runtime.h>
#include <math.h>

#define NBATCH 8
#define HWN (1024*1024)
#define NGRP (HWN/4)       // float4 groups per sample
#define AL(p) __hip_atomic_load((p), __ATOMIC_RELAXED, __HIP_MEMORY_SCOPE_AGENT)

// ---------- helpers ----------

static __device__ __forceinline__ float polar01(float x, float y) {
    // reference: (arctan(y/(x+1e-12)) + (x<0)*pi + ((x>0)&(y<0))*2pi) / (2pi)
    float r = y * __builtin_amdgcn_rcpf(x + 1e-12f);
    float ar = fabsf(r);
    float inv = __builtin_amdgcn_rcpf(ar);
    bool big = ar > 1.0f;
    float t = big ? inv : ar;
    float s = t * t;
    float p = -0.0117212f;
    p = fmaf(p, s,  0.05265332f);
    p = fmaf(p, s, -0.11643287f);
    p = fmaf(p, s,  0.19354346f);
    p = fmaf(p, s, -0.33262348f);
    p = fmaf(p, s,  0.99997726f);
    float a = t * p;
    a = big ? (1.57079632679489662f - a) : a;
    a = copysignf(a, r);
    if (x < 0.f) a += 3.14159274101257324f;
    else if (x > 0.f && y < 0.f) a += 6.28318548202514648f;
    return a * 0.15915494309189535f;
}

static __device__ __forceinline__ double block_reduce1(double a) {
    for (int o = 32; o; o >>= 1) a += __shfl_down(a, o);
    __shared__ double s[4];
    int w = threadIdx.x >> 6, l = threadIdx.x & 63;
    if (l == 0) s[w] = a;
    __syncthreads();
    double r = 0.0;
    if (threadIdx.x == 0) r = s[0] + s[1] + s[2] + s[3];
    __syncthreads();
    return r;
}

static __device__ __forceinline__ void block_reduce2(double& a, double& b) {
    for (int o = 32; o; o >>= 1) { a += __shfl_down(a, o); b += __shfl_down(b, o); }
    __shared__ double sa[4], sb[4];
    int wave = threadIdx.x >> 6, lane = threadIdx.x & 63;
    if (lane == 0) { sa[wave] = a; sb[wave] = b; }
    __syncthreads();
    if (threadIdx.x == 0) {
        a = sa[0] + sa[1] + sa[2] + sa[3];
        b = sb[0] + sb[1] + sb[2] + sb[3];
    }
    __syncthreads();
}

// ---------- kernel 1: ballot gt-histogram + stats tail ----------
// grid: 8192 blocks x 256 (one int4 per thread); blocks 1024*n .. cover sample n.
__global__ __launch_bounds__(256) void k_hist(const int* __restrict__ gt,
        unsigned* __restrict__ counts, float* __restrict__ pix, int* __restrict__ kv,
        double* __restrict__ g_wsum, unsigned* __restrict__ g_done) {
    int tid = threadIdx.x;
    int n = blockIdx.x >> 10;
    int j = (blockIdx.x & 1023) * 256 + tid;
    int4 g = ((const int4*)(gt + (size_t)n * HWN))[j];
    unsigned c[16];
#pragma unroll
    for (int b = 0; b < 16; ++b) c[b] = 0;
#pragma unroll
    for (int e = 0; e < 4; ++e) {
        int gv = (&g.x)[e] & 15;
#pragma unroll
        for (int b = 0; b < 16; ++b) c[b] += (unsigned)__popcll(__ballot(gv == b));
    }
    __shared__ unsigned sh[16];
    if (tid < 16) sh[tid] = 0u;
    __syncthreads();
    if ((tid & 63) == 0) {
#pragma unroll
        for (int b = 0; b < 16; ++b) atomicAdd(&sh[b], c[b]);
    }
    __syncthreads();
    if (tid < 16) atomicAdd(&counts[n * 16 + tid], sh[tid]);
    // ---- last-block tail: pix / k / wsum ----
    __threadfence();
    __shared__ bool last;
    if (tid == 0) last = (atomicAdd(g_done, 1u) == (unsigned)gridDim.x - 1u);
    __syncthreads();
    if (!last) return;
    double ws = 0.0;
    if (tid < 8) {
        int nn = tid;
        unsigned cc[16];
#pragma unroll
        for (int s = 0; s < 16; ++s) cc[s] = AL(&counts[nn * 16 + s]);
        long long sumPos = 0; int nseg = 0;
#pragma unroll
        for (int s = 1; s < 16; ++s) { sumPos += cc[s]; nseg += cc[s] ? 1 : 0; }
        long long sumNeg = cc[0];
        float seg_ave = (float)sumPos / (float)(nseg ? nseg : 1);
        pix[nn * 16] = 0.f;   // gt==0 -> weight 0
        for (int s = 1; s < 16; ++s) {
            float pv = seg_ave / (float)(cc[s] > 1u ? cc[s] : 1u);
            pix[nn * 16 + s] = pv;
            ws += (double)pv * (double)cc[s];
        }
        long long k = 3 * sumPos; if (sumNeg < k) k = sumNeg;
        kv[nn] = (int)k;
    }
    if (tid < 64) {
        for (int o = 4; o; o >>= 1) ws += __shfl_down(ws, o);
        if (tid == 0) *g_wsum = ws;
    }
}

// ---------- kernel 2: main fused pass + scanA tail ----------
// grid: 1024 blocks x 256; j = global thread id; loop n inside.
__global__ __launch_bounds__(256) void k_main(const float* __restrict__ pred,
        const float* __restrict__ gdf, const int* __restrict__ gt,
        const float* __restrict__ pix, const int* __restrict__ kv,
        float* __restrict__ lossBuf, unsigned short* __restrict__ tsumBuf,
        unsigned* __restrict__ h1G, double* __restrict__ g_num1,
        unsigned* __restrict__ g_done, unsigned* __restrict__ stMode,
        unsigned* __restrict__ stPfx, unsigned* __restrict__ stK,
        unsigned* __restrict__ stT) {
    __shared__ float spix[128];
    __shared__ unsigned h1[2048];
    int tid = threadIdx.x;
    if (tid < 128) spix[tid] = pix[tid];
    for (int i = tid; i < 2048; i += 256) h1[i] = 0u;
    __syncthreads();

    int j = blockIdx.x * 256 + tid;
    float tsum[4] = {0.f, 0.f, 0.f, 0.f};
    float num1f = 0.f;
#pragma unroll 2
    for (int n = 0; n < NBATCH; ++n) {
        float4 px4 = ((const float4*)(pred + ((size_t)(2 * n)    ) * HWN))[j];
        float4 py4 = ((const float4*)(pred + ((size_t)(2 * n) + 1) * HWN))[j];
        float4 gx4 = ((const float4*)(gdf  + ((size_t)(2 * n)    ) * HWN))[j];
        float4 gy4 = ((const float4*)(gdf  + ((size_t)(2 * n) + 1) * HWN))[j];
        int4   g4  = ((const int4*)  (gt   + (size_t)n * HWN))[j];
        float4 lossv;
#pragma unroll
        for (int e = 0; e < 4; ++e) {
            float px = (&px4.x)[e], py = (&py4.x)[e];
            float gx = (&gx4.x)[e], gy = (&gy4.x)[e];
            int   g  = (&g4.x)[e] & 15;
            float dx = px - gx, dy = py - gy;
            float ang = polar01(gx, gy) - polar01(px, py);
            float t = dx * dx + dy * dy + ang * ang;
            tsum[e] += t;
            num1f += t * spix[n * 16 + g];
            float lv = (g == 0) ? t : 0.f;
            (&lossv.x)[e] = lv;
            unsigned u = __float_as_uint(lv);
            if (u) atomicAdd(&h1[n * 256 + (u >> 24)], 1u);
        }
        ((float4*)(lossBuf + (size_t)n * HWN))[j] = lossv;
    }
    ushort4 tz;
#pragma unroll
    for (int e = 0; e < 4; ++e) {
        unsigned u = __float_as_uint(tsum[e]);
        (&tz.x)[e] = (unsigned short)((u + 0x7FFFu + ((u >> 16) & 1u)) >> 16);
    }
    ((ushort4*)tsumBuf)[j] = tz;

    double n1 = block_reduce1((double)num1f);
    if (tid == 0) atomicAdd(g_num1, n1);

    __syncthreads();
    int copy = blockIdx.x & 7;
    for (int i = tid; i < 2048; i += 256) {
        unsigned v = h1[i];
        if (v) atomicAdd(&h1G[copy * 2048 + i], v);
    }
    // ---- last-block tail: level-1 scan / threshold state ----
    __threadfence();
    __shared__ bool last;
    if (tid == 0) last = (atomicAdd(g_done, 1u) == (unsigned)gridDim.x - 1u);
    __syncthreads();
    if (!last) return;
    for (int i = tid; i < 2048; i += 256) {
        unsigned s = 0;
        for (int c = 0; c < 8; ++c) s += AL(&h1G[c * 2048 + i]);
        h1[i] = s;
    }
    __syncthreads();
    if (tid < 8) {
        int n = tid;
        const unsigned* h = &h1[n * 256];
        unsigned nnz = 0;
        for (int b = 0; b < 256; ++b) nnz += h[b];
        int k = kv[n];
        if (k <= 0)                 { stMode[n] = 0u; stT[n] = 0xFFFFFFFFu; stPfx[n] = 0u; stK[n] = 0u; }
        else if ((unsigned)k >= nnz){ stMode[n] = 0u; stT[n] = 0u;          stPfx[n] = 0u; stK[n] = 0u; }
        else {
            unsigned cum = 0; int b1 = 0;
            for (int b = 255; b >= 0; --b) { if (cum + h[b] >= (unsigned)k) { b1 = b; break; } cum += h[b]; }
            stMode[n] = 1u; stPfx[n] = (unsigned)b1; stK[n] = (unsigned)k - cum; stT[n] = 0u;
        }
    }
}

// ---------- kernel 3..5: 8-bit refinement levels, early-exit, scan tail ----------
__global__ __launch_bounds__(256) void k_refine(const float* __restrict__ lossBuf,
        unsigned* __restrict__ stMode, unsigned* __restrict__ stPfx,
        unsigned* __restrict__ stK, unsigned* __restrict__ stT,
        unsigned* __restrict__ hist, int level, unsigned* __restrict__ g_done) {
    unsigned md[NBATCH], pf[NBATCH]; bool any = false;
#pragma unroll
    for (int n = 0; n < NBATCH; ++n) {
        md[n] = stMode[n]; pf[n] = stPfx[n];
        any = any || (md[n] == (unsigned)level);
    }
    if (!any) return;   // uniform across grid
    int ms = 32 - 8 * level, hs = 24 - 8 * level;
    int stride = gridDim.x * blockDim.x;
    for (int j = blockIdx.x * blockDim.x + threadIdx.x; j < NGRP; j += stride) {
#pragma unroll
        for (int n = 0; n < NBATCH; ++n) {
            if (md[n] != (unsigned)level) continue;
            float4 lv = ((const float4*)(lossBuf + (size_t)n * HWN))[j];
#pragma unroll
            for (int e = 0; e < 4; ++e) {
                unsigned u = __float_as_uint((&lv.x)[e]);
                if (u != 0u && (u >> ms) == pf[n])
                    atomicAdd(&hist[n * 256 + ((u >> hs) & 255u)], 1u);
            }
        }
    }
    __threadfence();
    __shared__ bool last;
    if (threadIdx.x == 0) last = (atomicAdd(g_done, 1u) == (unsigned)gridDim.x - 1u);
    __syncthreads();
    if (!last) return;
    __shared__ unsigned sh[256];
    for (int n = 0; n < NBATCH; ++n) {
        if (md[n] != (unsigned)level) continue;
        sh[threadIdx.x] = AL(&hist[n * 256 + threadIdx.x]);
        __syncthreads();
        if (threadIdx.x == 0) {
            unsigned k2 = stK[n], cum = 0; int bb = 0;
            for (int b = 255; b >= 0; --b) { if (cum + sh[b] >= k2) { bb = b; break; } cum += sh[b]; }
            unsigned np = (pf[n] << 8) | (unsigned)bb;
            stK[n] = k2 - cum;
            if (level == 3) { stT[n] = np; stMode[n] = 0u; }
            else            { stPfx[n] = np; stMode[n] = (unsigned)(level + 1); }
        }
        __syncthreads();
    }
}

// ---------- kernel 6: num2/msum + final result tail ----------
// grid: 1024 blocks x 256, one j per thread.
__global__ __launch_bounds__(256) void k_num2(const float* __restrict__ lossBuf,
        const unsigned short* __restrict__ tsumBuf, const unsigned* __restrict__ stT,
        const double* __restrict__ g_num1, const double* __restrict__ g_wsum,
        double* __restrict__ g_acc, double* __restrict__ g_cnt,
        unsigned* __restrict__ g_done, float* __restrict__ out) {
    unsigned T[NBATCH];
#pragma unroll
    for (int n = 0; n < NBATCH; ++n) T[n] = stT[n];
    int j = blockIdx.x * 256 + threadIdx.x;
    ushort4 tz = ((const ushort4*)tsumBuf)[j];
    float ts[4];
#pragma unroll
    for (int e = 0; e < 4; ++e) ts[e] = __uint_as_float(((unsigned)(&tz.x)[e]) << 16);
    double acc = 0.0, cnt = 0.0;
#pragma unroll
    for (int n = 0; n < NBATCH; ++n) {
        float4 lv = ((const float4*)(lossBuf + (size_t)n * HWN))[j];
#pragma unroll
        for (int e = 0; e < 4; ++e) {
            unsigned u = __float_as_uint((&lv.x)[e]);
            if (u != 0u && u >= T[n]) { acc += (double)ts[e]; cnt += 1.0; }
        }
    }
    block_reduce2(acc, cnt);
    if (threadIdx.x == 0) { atomicAdd(g_acc, acc); atomicAdd(g_cnt, cnt); }
    __threadfence();
    __shared__ bool last;
    if (threadIdx.x == 0) last = (atomicAdd(g_done, 1u) == (unsigned)gridDim.x - 1u);
    __syncthreads();
    if (!last) return;
    if (threadIdx.x == 0) {
        double num2 = AL((double*)g_acc), msum = AL((double*)g_cnt);
        double num1 = g_num1[0], wsum = g_wsum[0];   // prior kernels: plain read ok
        double num = (double)NBATCH * num1 + num2;
        double denom = (double)NBATCH * (wsum + msum);
        out[0] = (float)(num / (double)NBATCH / 2.0 / denom);
    }
}

// ---------- launcher ----------

extern "C" void kernel_launch(void* const* d_in, const int* in_sizes, int n_in,
                              void* d_out, int out_size, void* d_ws, size_t ws_size,
                              hipStream_t stream) {
    const float* pred = (const float*)d_in[0];
    const float* gdf  = (const float*)d_in[1];
    const int*   gt   = (const int*)d_in[2];
    float* out = (float*)d_out;

    char* W = (char*)d_ws;
    float* lossBuf = (float*)W;                                   // 32 MiB
    unsigned short* tsumBuf = (unsigned short*)(W + 33554432);    // 2 MiB
    char* Z = W + 35651584;                                       // zeroed region
    unsigned* counts = (unsigned*)Z;              // 512 B
    unsigned* g_done = (unsigned*)(Z + 512);      // 8 x u32 (use 0..4)
    double*   g_num1 = (double*)(Z + 576);
    double*   g_wsum = (double*)(Z + 584);
    double*   g_acc  = (double*)(Z + 592);
    double*   g_cnt  = (double*)(Z + 600);
    unsigned* h1G    = (unsigned*)(Z + 1024);     // 8*2048*4 = 65536
    unsigned* hA     = (unsigned*)(Z + 66560);    // 8 KiB
    unsigned* hB     = (unsigned*)(Z + 74752);    // 8 KiB
    unsigned* hC     = (unsigned*)(Z + 82944);    // 8 KiB
    unsigned* stMode = (unsigned*)(Z + 91136);
    unsigned* stPfx  = (unsigned*)(Z + 91168);
    unsigned* stK    = (unsigned*)(Z + 91200);
    unsigned* stT    = (unsigned*)(Z + 91232);
    float*    pix    = (float*)(Z + 91264);       // 512 B
    int*      kv     = (int*)(Z + 91776);         // 32 B
    const size_t ZBYTES = 91904;

    size_t need = 35651584 + ZBYTES;
    if (ws_size < need) return;

    hipMemsetAsync(Z, 0, ZBYTES, stream);
    k_hist  <<<8192, 256, 0, stream>>>(gt, counts, pix, kv, g_wsum, &g_done[0]);
    k_main  <<<1024, 256, 0, stream>>>(pred, gdf, gt, pix, kv, lossBuf, tsumBuf,
                                       h1G, g_num1, &g_done[1], stMode, stPfx, stK, stT);
    k_refine<<<1024, 256, 0, stream>>>(lossBuf, stMode, stPfx, stK, stT, hA, 1, &g_done[2]);
    k_refine<<<1024, 256, 0, stream>>>(lossBuf, stMode, stPfx, stK, stT, hB, 2, &g_done[3]);
    k_refine<<<1024, 256, 0, stream>>>(lossBuf, stMode, stPfx, stK, stT, hC, 3, &g_done[4]);
    k_num2  <<<1024, 256, 0, stream>>>(lossBuf, tsumBuf, stT, g_num1, g_wsum,
                                       g_acc, g_cnt, &g_done[5], out);
}

// Round 6
// 223.095 us; speedup vs baseline: 4.3330x; 4.3330x over previous
//
#include <hip/hip_runtime.h>
#include <math.h>

#define NBATCH 8
#define HWN (1024*1024)
#define NGRP (HWN/4)       // float4 groups per sample
#define MAINB 1024

// ---------- helpers ----------

static __device__ __forceinline__ float polar01(float x, float y) {
    // reference: (arctan(y/(x+1e-12)) + (x<0)*pi + ((x>0)&(y<0))*2pi) / (2pi)
    float r = y * __builtin_amdgcn_rcpf(x + 1e-12f);
    float ar = fabsf(r);
    float inv = __builtin_amdgcn_rcpf(ar);
    bool big = ar > 1.0f;
    float t = big ? inv : ar;
    float s = t * t;
    float p = -0.0117212f;
    p = fmaf(p, s,  0.05265332f);
    p = fmaf(p, s, -0.11643287f);
    p = fmaf(p, s,  0.19354346f);
    p = fmaf(p, s, -0.33262348f);
    p = fmaf(p, s,  0.99997726f);
    float a = t * p;
    a = big ? (1.57079632679489662f - a) : a;
    a = copysignf(a, r);
    if (x < 0.f) a += 3.14159274101257324f;
    else if (x > 0.f && y < 0.f) a += 6.28318548202514648f;
    return a * 0.15915494309189535f;
}

static __device__ __forceinline__ void block_reduce2(double& a, double& b) {
    for (int o = 32; o; o >>= 1) { a += __shfl_down(a, o); b += __shfl_down(b, o); }
    __shared__ double sa[4], sb[4];
    int w = threadIdx.x >> 6, l = threadIdx.x & 63;
    if (l == 0) { sa[w] = a; sb[w] = b; }
    __syncthreads();
    if (threadIdx.x == 0) { a = sa[0]+sa[1]+sa[2]+sa[3]; b = sb[0]+sb[1]+sb[2]+sb[3]; }
    __syncthreads();
}

static __device__ __forceinline__ void block_reduce3(double& a, double& b, double& c) {
    for (int o = 32; o; o >>= 1) { a += __shfl_down(a, o); b += __shfl_down(b, o); c += __shfl_down(c, o); }
    __shared__ double sa[4], sb[4], sc[4];
    int w = threadIdx.x >> 6, l = threadIdx.x & 63;
    if (l == 0) { sa[w] = a; sb[w] = b; sc[w] = c; }
    __syncthreads();
    if (threadIdx.x == 0) {
        a = sa[0]+sa[1]+sa[2]+sa[3]; b = sb[0]+sb[1]+sb[2]+sb[3]; c = sc[0]+sc[1]+sc[2]+sc[3];
    }
    __syncthreads();
}

// ---------- kernel 1: ballot gt-histogram (no tail, replicated atomics) ----------
// grid: 2048 blocks x 256; block handles 1024 int4s of sample n = bid>>8.
__global__ __launch_bounds__(256) void k_hist(const int* __restrict__ gt,
        unsigned* __restrict__ countsRep) {
    int tid = threadIdx.x;
    int n = blockIdx.x >> 8;
    int jb = blockIdx.x & 255;
    const int4* g4 = (const int4*)(gt + (size_t)n * HWN);
    unsigned c[16];
#pragma unroll
    for (int b = 0; b < 16; ++b) c[b] = 0u;
#pragma unroll
    for (int k = 0; k < 4; ++k) {
        int4 g = g4[jb * 1024 + k * 256 + tid];
#pragma unroll
        for (int e = 0; e < 4; ++e) {
            int gv = (&g.x)[e] & 15;
#pragma unroll
            for (int b = 0; b < 16; ++b) c[b] += (unsigned)__popcll(__ballot(gv == b));
        }
    }
    // lane 0 of each wave: fire-and-forget atomics to a replicated copy
    if ((tid & 63) == 0) {
        int copy = (blockIdx.x * 4 + (tid >> 6)) & 31;
        unsigned* dst = countsRep + copy * 128 + n * 16;
#pragma unroll
        for (int b = 0; b < 16; ++b) atomicAdd(&dst[b], c[b]);
    }
}

// ---------- kernel 2: per-sample stats; decide per-sample mode ----------
// mode: 0 = ZERO (k<=0, contribute nothing), 1 = FAST (T=0, keep all loss!=0),
//       2 = SLOW (radix select needed)
__global__ void k_stats(const unsigned* __restrict__ countsRep, float* __restrict__ pix,
                        int* __restrict__ kv, int* __restrict__ mode,
                        double* __restrict__ g_wsum, unsigned* __restrict__ anySlow) {
    int tid = threadIdx.x;
    __shared__ unsigned sc[128];
    __shared__ int smd[NBATCH];
    __shared__ double sws[NBATCH];
    if (tid < 128) {
        unsigned s = 0;
        for (int c = 0; c < 32; ++c) s += countsRep[c * 128 + tid];
        sc[tid] = s;
    }
    __syncthreads();
    if (tid < NBATCH) {
        int n = tid;
        long long sumPos = 0; int nseg = 0;
        for (int s = 1; s < 16; ++s) { sumPos += sc[n*16+s]; nseg += sc[n*16+s] ? 1 : 0; }
        long long sumNeg = sc[n*16];
        float seg_ave = (float)sumPos / (float)(nseg ? nseg : 1);
        double ws = 0.0;
        pix[n*16] = 0.f;   // gt==0 -> weight 0
        for (int s = 1; s < 16; ++s) {
            unsigned cc = sc[n*16+s];
            float pv = seg_ave / (float)(cc > 1u ? cc : 1u);
            pix[n*16+s] = pv;
            ws += (double)pv * (double)cc;
        }
        long long k = 3 * sumPos; if (sumNeg < k) k = sumNeg;
        kv[n] = (int)k;
        int md = (k <= 0) ? 0 : ((k >= sumNeg) ? 1 : 2);
        mode[n] = md; smd[n] = md; sws[n] = ws;
    }
    __syncthreads();
    if (tid == 0) {
        double w = 0.0; unsigned as = 0u;
        for (int i = 0; i < NBATCH; ++i) { w += sws[i]; as |= (smd[i] == 2) ? 1u : 0u; }
        *g_wsum = w; *anySlow = as;
    }
}

// ---------- kernel 3: main fused pass ----------
// grid: MAINB x 256; thread owns pixel-group j across all n.
// Always: num1 += t*pix[gt]; tsum[e] += t; tsumBuf (bf16).
// FAST n: cntE[e] += (gt==0 && t!=0)  -> spec2/cntS in registers.
// SLOW n: lossBuf store + 8-bit MSB histogram (LDS -> 8 global copies).
__global__ __launch_bounds__(256) void k_main(const float* __restrict__ pred,
        const float* __restrict__ gdf, const int* __restrict__ gt,
        const float* __restrict__ pix, const int* __restrict__ mode,
        float* __restrict__ lossBuf, unsigned short* __restrict__ tsumBuf,
        unsigned* __restrict__ h1G, double* __restrict__ pN1,
        double* __restrict__ pS2, double* __restrict__ pC) {
    __shared__ float spix[128];
    __shared__ int smode[NBATCH];
    __shared__ unsigned h1[NBATCH * 256];
    int tid = threadIdx.x;
    if (tid < 128) spix[tid] = pix[tid];
    if (tid < NBATCH) smode[tid] = mode[tid];
    for (int i = tid; i < NBATCH * 256; i += 256) h1[i] = 0u;
    __syncthreads();

    int j = blockIdx.x * 256 + tid;
    float tsum[4] = {0.f, 0.f, 0.f, 0.f};
    int   cntE[4] = {0, 0, 0, 0};
    float num1f = 0.f;
#pragma unroll 2
    for (int n = 0; n < NBATCH; ++n) {
        float4 px4 = ((const float4*)(pred + ((size_t)(2 * n)    ) * HWN))[j];
        float4 py4 = ((const float4*)(pred + ((size_t)(2 * n) + 1) * HWN))[j];
        float4 gx4 = ((const float4*)(gdf  + ((size_t)(2 * n)    ) * HWN))[j];
        float4 gy4 = ((const float4*)(gdf  + ((size_t)(2 * n) + 1) * HWN))[j];
        int4   g4  = ((const int4*)  (gt   + (size_t)n * HWN))[j];
        int m = smode[n];
        float4 lossv;
#pragma unroll
        for (int e = 0; e < 4; ++e) {
            float px = (&px4.x)[e], py = (&py4.x)[e];
            float gx = (&gx4.x)[e], gy = (&gy4.x)[e];
            int   g  = (&g4.x)[e] & 15;
            float dx = px - gx, dy = py - gy;
            float ang = polar01(gx, gy) - polar01(px, py);
            float t = dx * dx + dy * dy + ang * ang;
            tsum[e] += t;
            num1f += t * spix[n * 16 + g];
            if (m == 1) {
                if (g == 0 && t != 0.f) cntE[e]++;
            } else if (m == 2) {
                float lv = (g == 0) ? t : 0.f;
                (&lossv.x)[e] = lv;
                unsigned u = __float_as_uint(lv);
                if (u) atomicAdd(&h1[n * 256 + (u >> 24)], 1u);
            }
        }
        if (m == 2) ((float4*)(lossBuf + (size_t)n * HWN))[j] = lossv;
    }
    // tsum -> bf16 (RNE), for the (rare) slow path
    ushort4 tz;
#pragma unroll
    for (int e = 0; e < 4; ++e) {
        unsigned u = __float_as_uint(tsum[e]);
        (&tz.x)[e] = (unsigned short)((u + 0x7FFFu + ((u >> 16) & 1u)) >> 16);
    }
    ((ushort4*)tsumBuf)[j] = tz;

    float spec2 = 0.f, cntS = 0.f;
#pragma unroll
    for (int e = 0; e < 4; ++e) { spec2 += tsum[e] * (float)cntE[e]; cntS += (float)cntE[e]; }

    double a = (double)num1f, b = (double)spec2, c = (double)cntS;
    block_reduce3(a, b, c);
    if (tid == 0) { pN1[blockIdx.x] = a; pS2[blockIdx.x] = b; pC[blockIdx.x] = c; }

    __syncthreads();
    int copy = blockIdx.x & 7;
    for (int i = tid; i < NBATCH * 256; i += 256) {
        unsigned v = h1[i];
        if (v) atomicAdd(&h1G[copy * 2048 + i], v);
    }
}

// ---------- kernel 4: combine partials + level-1 scan for slow samples ----------
__global__ void k_scanA(const unsigned* __restrict__ h1G, const int* __restrict__ kv,
        const int* __restrict__ mode, unsigned* __restrict__ stMode,
        unsigned* __restrict__ stPfx, unsigned* __restrict__ stK,
        unsigned* __restrict__ stT, unsigned* __restrict__ active,
        const double* __restrict__ pN1, const double* __restrict__ pS2,
        const double* __restrict__ pC, double* __restrict__ g_num1,
        double* __restrict__ g_acc, double* __restrict__ g_cnt) {
    int tid = threadIdx.x;
    double a = 0, b = 0, c = 0;
    for (int i = tid; i < MAINB; i += 256) { a += pN1[i]; b += pS2[i]; c += pC[i]; }
    block_reduce3(a, b, c);
    if (tid == 0) { *g_num1 = a; *g_acc = b; *g_cnt = c; }
    __shared__ unsigned h[256];
    __shared__ unsigned rw[4];
    for (int n = 0; n < NBATCH; ++n) {
        if (mode[n] != 2) continue;       // block-uniform
        unsigned s = 0;
        for (int c8 = 0; c8 < 8; ++c8) s += h1G[c8 * 2048 + n * 256 + tid];
        h[tid] = s;
        unsigned v = s;
        for (int o = 32; o; o >>= 1) v += __shfl_down(v, o);
        int w = tid >> 6, l = tid & 63;
        if (l == 0) rw[w] = v;
        __syncthreads();
        if (tid == 0) {
            unsigned nnz = rw[0] + rw[1] + rw[2] + rw[3];
            unsigned k = (unsigned)kv[n];
            if (k >= nnz) { stT[n] = 0u; stMode[n] = 0u; }
            else {
                unsigned cum = 0; int b1 = 0;
                for (int bb = 255; bb >= 0; --bb) { if (cum + h[bb] >= k) { b1 = bb; break; } cum += h[bb]; }
                stMode[n] = 1u; stPfx[n] = (unsigned)b1; stK[n] = k - cum; active[1] = 1u;
            }
        }
        __syncthreads();
    }
}

// ---------- kernels 5..7: gated 8-bit refinement ----------
__global__ __launch_bounds__(256) void k_refine(const float* __restrict__ lossBuf,
        const unsigned* __restrict__ stMode, const unsigned* __restrict__ stPfx,
        unsigned* __restrict__ hist, int level, const unsigned* __restrict__ active) {
    if (active[level] == 0u) return;      // broadcast load, ~1us when inactive
    unsigned md[NBATCH], pf[NBATCH];
#pragma unroll
    for (int n = 0; n < NBATCH; ++n) { md[n] = stMode[n]; pf[n] = stPfx[n]; }
    int ms = 32 - 8 * level, hs = 24 - 8 * level;
    int stride = gridDim.x * blockDim.x;
    for (int j = blockIdx.x * blockDim.x + threadIdx.x; j < NGRP; j += stride) {
#pragma unroll
        for (int n = 0; n < NBATCH; ++n) {
            if (md[n] != (unsigned)level) continue;
            float4 lv = ((const float4*)(lossBuf + (size_t)n * HWN))[j];
#pragma unroll
            for (int e = 0; e < 4; ++e) {
                unsigned u = __float_as_uint((&lv.x)[e]);
                if (u != 0u && (u >> ms) == pf[n])
                    atomicAdd(&hist[n * 256 + ((u >> hs) & 255u)], 1u);
            }
        }
    }
}

__global__ void k_scanN(unsigned* __restrict__ stMode, unsigned* __restrict__ stPfx,
        unsigned* __restrict__ stK, unsigned* __restrict__ stT,
        const unsigned* __restrict__ hist, int level, unsigned* __restrict__ active) {
    if (active[level] == 0u) return;
    int n = blockIdx.x;
    if (stMode[n] != (unsigned)level) return;
    __shared__ unsigned h[256];
    h[threadIdx.x] = hist[n * 256 + threadIdx.x];
    __syncthreads();
    if (threadIdx.x == 0) {
        unsigned k2 = stK[n], cum = 0; int bb = 0;
        for (int b = 255; b >= 0; --b) { if (cum + h[b] >= k2) { bb = b; break; } cum += h[b]; }
        unsigned np = (stPfx[n] << 8) | (unsigned)bb;
        stK[n] = k2 - cum;
        if (level == 3) { stT[n] = np; stMode[n] = 0u; }
        else            { stPfx[n] = np; stMode[n] = (unsigned)(level + 1); active[level + 1] = 1u; }
    }
}

// ---------- kernel 8: slow-sample num2/msum (gated) ----------
__global__ __launch_bounds__(256) void k_num2(const float* __restrict__ lossBuf,
        const unsigned short* __restrict__ tsumBuf, const unsigned* __restrict__ stT,
        const int* __restrict__ mode, const unsigned* __restrict__ anySlow,
        double* __restrict__ g_acc, double* __restrict__ g_cnt) {
    if (*anySlow == 0u) return;
    int j = blockIdx.x * 256 + threadIdx.x;
    ushort4 tz = ((const ushort4*)tsumBuf)[j];
    float ts[4];
#pragma unroll
    for (int e = 0; e < 4; ++e) ts[e] = __uint_as_float(((unsigned)(&tz.x)[e]) << 16);
    double acc = 0.0, cnt = 0.0;
#pragma unroll
    for (int n = 0; n < NBATCH; ++n) {
        if (mode[n] != 2) continue;
        unsigned T = stT[n];
        float4 lv = ((const float4*)(lossBuf + (size_t)n * HWN))[j];
#pragma unroll
        for (int e = 0; e < 4; ++e) {
            unsigned u = __float_as_uint((&lv.x)[e]);
            if (u != 0u && u >= T) { acc += (double)ts[e]; cnt += 1.0; }
        }
    }
    block_reduce2(acc, cnt);
    if (threadIdx.x == 0) { atomicAdd(g_acc, acc); atomicAdd(g_cnt, cnt); }
}

// ---------- kernel 9: final scalar ----------
__global__ void k_result(const double* __restrict__ g_num1, const double* __restrict__ g_wsum,
        const double* __restrict__ g_acc, const double* __restrict__ g_cnt,
        float* __restrict__ out) {
    double num = (double)NBATCH * g_num1[0] + g_acc[0];
    double den = (double)NBATCH * (g_wsum[0] + g_cnt[0]);
    out[0] = (float)(num / (double)NBATCH / 2.0 / den);
}

// ---------- launcher ----------

extern "C" void kernel_launch(void* const* d_in, const int* in_sizes, int n_in,
                              void* d_out, int out_size, void* d_ws, size_t ws_size,
                              hipStream_t stream) {
    const float* pred = (const float*)d_in[0];
    const float* gdf  = (const float*)d_in[1];
    const int*   gt   = (const int*)d_in[2];
    float* out = (float*)d_out;

    char* W = (char*)d_ws;
    float* lossBuf = (float*)W;                                   // 32 MiB (slow path only)
    unsigned short* tsumBuf = (unsigned short*)(W + 33554432);    // 2 MiB
    char* Z = W + 35651584;                                       // zeroed region
    unsigned* countsRep = (unsigned*)Z;               // 32*128*4 = 16384
    unsigned* h1G    = (unsigned*)(Z + 16384);        // 8*2048*4 = 65536 -> 81920
    unsigned* hA     = (unsigned*)(Z + 81920);        // 8192 -> 90112
    unsigned* hB     = (unsigned*)(Z + 90112);        // 8192 -> 98304
    unsigned* hC     = (unsigned*)(Z + 98304);        // 8192 -> 106496
    unsigned* stMode = (unsigned*)(Z + 106496);       // 32
    unsigned* stPfx  = (unsigned*)(Z + 106528);       // 32
    unsigned* stK    = (unsigned*)(Z + 106560);       // 32
    unsigned* stT    = (unsigned*)(Z + 106592);       // 32
    unsigned* active = (unsigned*)(Z + 106624);       // 16
    unsigned* anySlow= (unsigned*)(Z + 106640);       // 4 (+4 pad)
    double*   g_num1 = (double*)(Z + 106648);
    double*   g_wsum = (double*)(Z + 106656);
    double*   g_acc  = (double*)(Z + 106664);
    double*   g_cnt  = (double*)(Z + 106672);
    const size_t ZBYTES = 106680;
    char* P = Z + ZBYTES;                             // not zeroed (fully overwritten)
    float* pix  = (float*)P;                          // 512
    int*   kv   = (int*)(P + 512);                    // 32
    int*   mode = (int*)(P + 544);                    // 32 (+pad to 576)
    double* pN1 = (double*)(P + 576);                 // 8192
    double* pS2 = (double*)(P + 8768);                // 8192
    double* pC  = (double*)(P + 16960);               // 8192 -> end P+25152

    size_t need = 35651584 + ZBYTES + 25152;
    if (ws_size < need) return;

    hipMemsetAsync(Z, 0, ZBYTES, stream);
    k_hist  <<<2048, 256, 0, stream>>>(gt, countsRep);
    k_stats <<<1, 256, 0, stream>>>(countsRep, pix, kv, mode, g_wsum, anySlow);
    k_main  <<<MAINB, 256, 0, stream>>>(pred, gdf, gt, pix, mode, lossBuf, tsumBuf,
                                        h1G, pN1, pS2, pC);
    k_scanA <<<1, 256, 0, stream>>>(h1G, kv, mode, stMode, stPfx, stK, stT, active,
                                    pN1, pS2, pC, g_num1, g_acc, g_cnt);
    k_refine<<<1024, 256, 0, stream>>>(lossBuf, stMode, stPfx, hA, 1, active);
    k_scanN <<<NBATCH, 256, 0, stream>>>(stMode, stPfx, stK, stT, hA, 1, active);
    k_refine<<<1024, 256, 0, stream>>>(lossBuf, stMode, stPfx, hB, 2, active);
    k_scanN <<<NBATCH, 256, 0, stream>>>(stMode, stPfx, stK, stT, hB, 2, active);
    k_refine<<<1024, 256, 0, stream>>>(lossBuf, stMode, stPfx, hC, 3, active);
    k_scanN <<<NBATCH, 256, 0, stream>>>(stMode, stPfx, stK, stT, hC, 3, active);
    k_num2  <<<MAINB, 256, 0, stream>>>(lossBuf, tsumBuf, stT, mode, anySlow, g_acc, g_cnt);
    k_result<<<1, 1, 0, stream>>>(g_num1, g_wsum, g_acc, g_cnt, out);
}

// Round 9
// 221.308 us; speedup vs baseline: 4.3680x; 1.0081x over previous
//
#include <hip/hip_runtime.h>
#include <math.h>

#define NBATCH 8
#define HWN (1024*1024)
#define NPAIR (HWN/2)      // float2 pairs per sample
#define HB 512             // k_hist blocks (64 per sample)
#define MB 2048            // k_main blocks

// ---------- helpers ----------

static __device__ __forceinline__ float polar01(float x, float y) {
    // reference: (arctan(y/(x+1e-12)) + (x<0)*pi + ((x>0)&(y<0))*2pi) / (2pi)
    float r = y * __builtin_amdgcn_rcpf(x + 1e-12f);
    float ar = fabsf(r);
    float inv = __builtin_amdgcn_rcpf(ar);
    bool big = ar > 1.0f;
    float t = big ? inv : ar;
    float s = t * t;
    float p = -0.0117212f;
    p = fmaf(p, s,  0.05265332f);
    p = fmaf(p, s, -0.11643287f);
    p = fmaf(p, s,  0.19354346f);
    p = fmaf(p, s, -0.33262348f);
    p = fmaf(p, s,  0.99997726f);
    float a = t * p;
    a = big ? (1.57079632679489662f - a) : a;
    a = copysignf(a, r);
    if (x < 0.f) a += 3.14159274101257324f;
    else if (x > 0.f && y < 0.f) a += 6.28318548202514648f;
    return a * 0.15915494309189535f;
}

static __device__ __forceinline__ void block_reduce2(double& a, double& b) {
    for (int o = 32; o; o >>= 1) { a += __shfl_down(a, o); b += __shfl_down(b, o); }
    __shared__ double sa[4], sb[4];
    int w = threadIdx.x >> 6, l = threadIdx.x & 63;
    if (l == 0) { sa[w] = a; sb[w] = b; }
    __syncthreads();
    if (threadIdx.x == 0) { a = sa[0]+sa[1]+sa[2]+sa[3]; b = sb[0]+sb[1]+sb[2]+sb[3]; }
    __syncthreads();
}

static __device__ __forceinline__ void block_reduce3(double& a, double& b, double& c) {
    for (int o = 32; o; o >>= 1) { a += __shfl_down(a, o); b += __shfl_down(b, o); c += __shfl_down(c, o); }
    __shared__ double sa[4], sb[4], sc4[4];
    int w = threadIdx.x >> 6, l = threadIdx.x & 63;
    if (l == 0) { sa[w] = a; sb[w] = b; sc4[w] = c; }
    __syncthreads();
    if (threadIdx.x == 0) {
        a = sa[0]+sa[1]+sa[2]+sa[3]; b = sb[0]+sb[1]+sb[2]+sb[3]; c = sc4[0]+sc4[1]+sc4[2]+sc4[3];
    }
    __syncthreads();
}

// Per-sample stats from the 512 per-block histogram slots (hcntT[bin][512]).
// Fills sc[128] (per-sample 16-bin counts) and smode[8]; caller syncs.
static __device__ __forceinline__ void load_counts(const unsigned* __restrict__ hcntT,
                                                   unsigned* sc) {
    int tid = threadIdx.x;
    if (tid < 128) {
        int n = tid >> 4, bin = tid & 15;
        const uint4* p = (const uint4*)&hcntT[bin * HB + n * 64];
        unsigned s = 0;
#pragma unroll
        for (int k = 0; k < 16; ++k) { uint4 v = p[k]; s += v.x + v.y + v.z + v.w; }
        sc[tid] = s;
    }
}

// ---------- kernel 1: per-block ballot gt-histogram + zero h64 ----------
// grid: HB x 256; block b handles sample n=b>>6, 4096 int4s.
__global__ __launch_bounds__(256) void k_hist(const int* __restrict__ gt,
        unsigned* __restrict__ hcntT, unsigned* __restrict__ h64) {
    int tid = threadIdx.x;
    // zero the slow-path histogram: 8*65536 u32 = 131072 uint4 = HB*256
    uint4 z; z.x = z.y = z.z = z.w = 0u;
    ((uint4*)h64)[blockIdx.x * 256 + tid] = z;

    int n = blockIdx.x >> 6, b = blockIdx.x & 63;
    const int4* g4 = (const int4*)(gt + (size_t)n * HWN);
    unsigned c[16];
#pragma unroll
    for (int bin = 0; bin < 16; ++bin) c[bin] = 0u;
#pragma unroll
    for (int k = 0; k < 16; ++k) {
        int4 g = g4[b * 4096 + k * 256 + tid];
#pragma unroll
        for (int e = 0; e < 4; ++e) {
            int gv = (&g.x)[e] & 15;
#pragma unroll
            for (int bin = 0; bin < 16; ++bin)
                c[bin] += (unsigned)__popcll(__ballot(gv == bin));
        }
    }
    __shared__ unsigned sw[4][16];
    int wave = tid >> 6, lane = tid & 63;
    if (lane == 0) {
#pragma unroll
        for (int bin = 0; bin < 16; ++bin) sw[wave][bin] = c[bin];
    }
    __syncthreads();
    if (tid < 16) hcntT[tid * HB + blockIdx.x] = sw[0][tid] + sw[1][tid] + sw[2][tid] + sw[3][tid];
}

// ---------- kernel 2: main fused pass (stats inlined, FAST num2 in registers) ----------
// grid: MB x 256; thread owns pixel pair j2 across all n.
__global__ __launch_bounds__(256, 8) void k_main(const float* __restrict__ pred,
        const float* __restrict__ gdf, const int* __restrict__ gt,
        const unsigned* __restrict__ hcntT, float* __restrict__ lossBuf,
        unsigned short* __restrict__ tsumBuf, unsigned* __restrict__ h64,
        double* __restrict__ pN1, double* __restrict__ pS2, double* __restrict__ pC) {
    __shared__ unsigned sc[128];
    __shared__ float spix[128];
    __shared__ int smode[NBATCH];
    __shared__ int sAny;
    int tid = threadIdx.x;
    load_counts(hcntT, sc);
    if (tid == 0) sAny = 0;
    __syncthreads();
    if (tid < NBATCH) {
        int n = tid;
        long long sumPos = 0; int nseg = 0;
        for (int s = 1; s < 16; ++s) { sumPos += sc[n*16+s]; nseg += sc[n*16+s] ? 1 : 0; }
        long long sumNeg = sc[n*16];
        float seg_ave = (float)sumPos / (float)(nseg ? nseg : 1);
        spix[n*16] = 0.f;
        for (int s = 1; s < 16; ++s) {
            unsigned cc = sc[n*16+s];
            spix[n*16+s] = seg_ave / (float)(cc > 1u ? cc : 1u);
        }
        long long k = 3 * sumPos; if (sumNeg < k) k = sumNeg;
        int md = (k <= 0) ? 0 : ((k >= sumNeg) ? 1 : 2);
        smode[n] = md;
        if (md == 2) sAny = 1;
    }
    __syncthreads();
    bool anySlow = (sAny != 0);

    int j2 = blockIdx.x * 256 + tid;   // 0 .. NPAIR-1
    float ts0 = 0.f, ts1 = 0.f, num1f = 0.f;
    int c0 = 0, c1 = 0;
#pragma unroll 2
    for (int n = 0; n < NBATCH; ++n) {
        float2 px2 = ((const float2*)(pred + ((size_t)(2*n)    ) * HWN))[j2];
        float2 py2 = ((const float2*)(pred + ((size_t)(2*n) + 1) * HWN))[j2];
        float2 gx2 = ((const float2*)(gdf  + ((size_t)(2*n)    ) * HWN))[j2];
        float2 gy2 = ((const float2*)(gdf  + ((size_t)(2*n) + 1) * HWN))[j2];
        int2   g2  = ((const int2*)  (gt   + (size_t)n * HWN))[j2];
        int m = smode[n];
        float dx0 = px2.x - gx2.x, dy0 = py2.x - gy2.x;
        float a0 = polar01(gx2.x, gy2.x) - polar01(px2.x, py2.x);
        float t0 = dx0*dx0 + dy0*dy0 + a0*a0;
        float dx1 = px2.y - gx2.y, dy1 = py2.y - gy2.y;
        float a1 = polar01(gx2.y, gy2.y) - polar01(px2.y, py2.y);
        float t1 = dx1*dx1 + dy1*dy1 + a1*a1;
        int gv0 = g2.x & 15, gv1 = g2.y & 15;
        ts0 += t0; ts1 += t1;
        num1f += t0 * spix[n*16 + gv0];
        num1f += t1 * spix[n*16 + gv1];
        if (m == 1) {
            c0 += (gv0 == 0 && t0 != 0.f) ? 1 : 0;
            c1 += (gv1 == 0 && t1 != 0.f) ? 1 : 0;
        } else if (m == 2) {
            float l0 = (gv0 == 0) ? t0 : 0.f;
            float l1 = (gv1 == 0) ? t1 : 0.f;
            float2 lv; lv.x = l0; lv.y = l1;
            ((float2*)(lossBuf + (size_t)n * HWN))[j2] = lv;
            unsigned u0 = __float_as_uint(l0), u1 = __float_as_uint(l1);
            unsigned* hh = h64 + (size_t)(blockIdx.x & 7) * 65536;
            if (u0) atomicAdd(&hh[u0 >> 16], 1u);
            if (u1) atomicAdd(&hh[u1 >> 16], 1u);
        }
    }
    if (anySlow) {
        // tsum -> bf16 (RNE) for the slow-path re-scan
        unsigned u0 = __float_as_uint(ts0), u1 = __float_as_uint(ts1);
        ushort2 tz;
        tz.x = (unsigned short)((u0 + 0x7FFFu + ((u0 >> 16) & 1u)) >> 16);
        tz.y = (unsigned short)((u1 + 0x7FFFu + ((u1 >> 16) & 1u)) >> 16);
        ((ushort2*)tsumBuf)[j2] = tz;
    }
    double a = (double)num1f;
    double b = (double)(ts0 * (float)c0 + ts1 * (float)c1);
    double c = (double)(c0 + c1);
    block_reduce3(a, b, c);
    if (tid == 0) { pN1[blockIdx.x] = a; pS2[blockIdx.x] = b; pC[blockIdx.x] = c; }
}

// ---------- kernel 3: single-block tail: combine + slow-path select + result ----------
__global__ __launch_bounds__(256) void k_tail(const unsigned* __restrict__ hcntT,
        const unsigned* __restrict__ h64, const float* __restrict__ lossBuf,
        const unsigned short* __restrict__ tsumBuf, const double* __restrict__ pN1,
        const double* __restrict__ pS2, const double* __restrict__ pC,
        float* __restrict__ out) {
    __shared__ unsigned sc[128];
    __shared__ double swsum[NBATCH];
    __shared__ int smode[NBATCH];
    __shared__ long long skv[NBATCH];
    __shared__ unsigned part[256];
    __shared__ unsigned fine[256];
    __shared__ unsigned scoarse[2];   // [0]=coarse bucket, [1]=cumAbove
    __shared__ double racc[2];
    int tid = threadIdx.x;
    load_counts(hcntT, sc);
    __syncthreads();
    if (tid < NBATCH) {
        int n = tid;
        long long sumPos = 0; int nseg = 0;
        for (int s = 1; s < 16; ++s) { sumPos += sc[n*16+s]; nseg += sc[n*16+s] ? 1 : 0; }
        long long sumNeg = sc[n*16];
        float seg_ave = (float)sumPos / (float)(nseg ? nseg : 1);
        double ws = 0.0;
        for (int s = 1; s < 16; ++s) {
            unsigned cc = sc[n*16+s];
            float pv = seg_ave / (float)(cc > 1u ? cc : 1u);
            ws += (double)pv * (double)cc;
        }
        long long k = 3 * sumPos; if (sumNeg < k) k = sumNeg;
        skv[n] = k;
        smode[n] = (k <= 0) ? 0 : ((k >= sumNeg) ? 1 : 2);
        swsum[n] = ws;
    }
    __syncthreads();

    // combine k_main partials
    double a = 0, b = 0, c = 0;
    for (int i = tid; i < MB; i += 256) { a += pN1[i]; b += pS2[i]; c += pC[i]; }
    block_reduce3(a, b, c);
    if (tid == 0) { racc[0] = b; racc[1] = c; }   // num2, msum (fast part)
    __syncthreads();

    // slow samples: find 16-bit-bucket threshold, then stream lossBuf
    for (int n = 0; n < NBATCH; ++n) {
        if (smode[n] != 2) continue;
        unsigned loc = 0;
        int base = tid * 256;
        for (int i = 0; i < 256; ++i) {
            unsigned s = 0;
#pragma unroll
            for (int r = 0; r < 8; ++r) s += h64[r * 65536 + base + i];
            loc += s;
        }
        part[tid] = loc;
        __syncthreads();
        if (tid == 0) {
            long long nnz = 0;
            for (int i = 0; i < 256; ++i) nnz += part[i];
            long long k = skv[n];
            if (k >= nnz) { scoarse[0] = 0xFFFFFFFFu; }   // keep all nonzero (T=0)
            else {
                unsigned cum = 0; int cc2 = 0;
                for (int i = 255; i >= 0; --i) {
                    if ((long long)cum + part[i] >= k) { cc2 = i; break; }
                    cum += part[i];
                }
                scoarse[0] = (unsigned)cc2; scoarse[1] = cum;
            }
        }
        __syncthreads();
        unsigned T = 0u;
        if (scoarse[0] != 0xFFFFFFFFu) {
            unsigned cc2 = scoarse[0];
            unsigned s = 0;
#pragma unroll
            for (int r = 0; r < 8; ++r) s += h64[r * 65536 + cc2 * 256 + tid];
            fine[tid] = s;
            __syncthreads();
            if (tid == 0) {
                long long k = skv[n];
                unsigned cum = scoarse[1]; int bb = 0;
                for (int i = 255; i >= 0; --i) {
                    if ((long long)cum + fine[i] >= k) { bb = i; break; }
                    cum += fine[i];
                }
                scoarse[0] = (scoarse[0] << 8) | (unsigned)bb;   // 16-bit bucket
            }
            __syncthreads();
            T = scoarse[0] << 16;
            __syncthreads();
        }
        // stream this sample's loss + tsum
        double acc = 0.0, cnt = 0.0;
        const float2* lp = (const float2*)(lossBuf + (size_t)n * HWN);
        const ushort2* tp = (const ushort2*)tsumBuf;
        for (int i = tid; i < NPAIR; i += 256) {
            float2 lv = lp[i];
            ushort2 tz = tp[i];
            unsigned u0 = __float_as_uint(lv.x), u1 = __float_as_uint(lv.y);
            if (u0 != 0u && u0 >= T) { acc += (double)__uint_as_float(((unsigned)tz.x) << 16); cnt += 1.0; }
            if (u1 != 0u && u1 >= T) { acc += (double)__uint_as_float(((unsigned)tz.y) << 16); cnt += 1.0; }
        }
        block_reduce2(acc, cnt);
        if (tid == 0) { racc[0] += acc; racc[1] += cnt; }
        __syncthreads();
    }

    if (tid == 0) {
        double wsum = 0.0;
        for (int n = 0; n < NBATCH; ++n) wsum += swsum[n];
        double num = (double)NBATCH * a + racc[0];
        double den = (double)NBATCH * (wsum + racc[1]);
        out[0] = (float)(num / (double)NBATCH / 2.0 / den);
    }
}

// ---------- launcher: 3 dispatch nodes, no memset ----------

extern "C" void kernel_launch(void* const* d_in, const int* in_sizes, int n_in,
                              void* d_out, int out_size, void* d_ws, size_t ws_size,
                              hipStream_t stream) {
    const float* pred = (const float*)d_in[0];
    const float* gdf  = (const float*)d_in[1];
    const int*   gt   = (const int*)d_in[2];
    float* out = (float*)d_out;

    char* W = (char*)d_ws;
    float* lossBuf = (float*)W;                                   // 32 MiB (slow path only)
    unsigned short* tsumBuf = (unsigned short*)(W + 33554432);    // 2 MiB (slow path only)
    unsigned* h64   = (unsigned*)(W + 35651584);                  // 8*65536*4 = 2 MiB
    unsigned* hcntT = (unsigned*)(W + 37748736);                  // 16*512*4 = 32 KiB
    double*   pN1   = (double*)(W + 37781504);                    // MB doubles = 16 KiB
    double*   pS2   = pN1 + MB;
    double*   pC    = pS2 + MB;

    size_t need = 37781504 + (size_t)3 * MB * 8;
    if (ws_size < need) return;

    k_hist<<<HB, 256, 0, stream>>>(gt, hcntT, h64);
    k_main<<<MB, 256, 0, stream>>>(pred, gdf, gt, hcntT, lossBuf, tsumBuf, h64, pN1, pS2, pC);
    k_tail<<<1, 256, 0, stream>>>(hcntT, h64, lossBuf, tsumBuf, pN1, pS2, pC, out);
}

// Round 13
// 215.410 us; speedup vs baseline: 4.4876x; 1.0274x over previous
//
#include <hip/hip_runtime.h>
#include <math.h>

#define NBATCH 8
#define HWN (1024*1024)
#define NGRP (HWN/4)       // float4 groups per sample
#define NPAIR (HWN/2)      // float2 pairs per sample (k_tail streaming)
#define HB 512             // k_hist blocks (64 per sample)
#define MB 1024            // k_main blocks (4 px/thread)

// ---------- helpers ----------

static __device__ __forceinline__ float polar01(float x, float y) {
    // reference: (arctan(y/(x+1e-12)) + (x<0)*pi + ((x>0)&(y<0))*2pi) / (2pi)
    float r = y * __builtin_amdgcn_rcpf(x + 1e-12f);
    float ar = fabsf(r);
    float inv = __builtin_amdgcn_rcpf(ar);
    bool big = ar > 1.0f;
    float t = big ? inv : ar;
    float s = t * t;
    float p = -0.0117212f;
    p = fmaf(p, s,  0.05265332f);
    p = fmaf(p, s, -0.11643287f);
    p = fmaf(p, s,  0.19354346f);
    p = fmaf(p, s, -0.33262348f);
    p = fmaf(p, s,  0.99997726f);
    float a = t * p;
    a = big ? (1.57079632679489662f - a) : a;
    a = copysignf(a, r);
    if (x < 0.f) a += 3.14159274101257324f;
    else if (x > 0.f && y < 0.f) a += 6.28318548202514648f;
    return a * 0.15915494309189535f;
}

static __device__ __forceinline__ void block_reduce2(double& a, double& b) {
    for (int o = 32; o; o >>= 1) { a += __shfl_down(a, o); b += __shfl_down(b, o); }
    __shared__ double sa[4], sb[4];
    int w = threadIdx.x >> 6, l = threadIdx.x & 63;
    if (l == 0) { sa[w] = a; sb[w] = b; }
    __syncthreads();
    if (threadIdx.x == 0) { a = sa[0]+sa[1]+sa[2]+sa[3]; b = sb[0]+sb[1]+sb[2]+sb[3]; }
    __syncthreads();
}

static __device__ __forceinline__ void block_reduce3(double& a, double& b, double& c) {
    for (int o = 32; o; o >>= 1) { a += __shfl_down(a, o); b += __shfl_down(b, o); c += __shfl_down(c, o); }
    __shared__ double sa[4], sb[4], sc4[4];
    int w = threadIdx.x >> 6, l = threadIdx.x & 63;
    if (l == 0) { sa[w] = a; sb[w] = b; sc4[w] = c; }
    __syncthreads();
    if (threadIdx.x == 0) {
        a = sa[0]+sa[1]+sa[2]+sa[3]; b = sb[0]+sb[1]+sb[2]+sb[3]; c = sc4[0]+sc4[1]+sc4[2]+sc4[3];
    }
    __syncthreads();
}

// Per-sample 16-bin counts from the 512 per-block histogram slots (hcntT[bin][512]).
static __device__ __forceinline__ void load_counts(const unsigned* __restrict__ hcntT,
                                                   unsigned* sc) {
    int tid = threadIdx.x;
    if (tid < 128) {
        int n = tid >> 4, bin = tid & 15;
        const uint4* p = (const uint4*)&hcntT[bin * HB + n * 64];
        unsigned s = 0;
#pragma unroll
        for (int k = 0; k < 16; ++k) { uint4 v = p[k]; s += v.x + v.y + v.z + v.w; }
        sc[tid] = s;
    }
}

// ---------- kernel 1: per-block ballot gt-histogram + zero h64 ----------
// grid: HB x 256; block b handles sample n=b>>6, 4096 int4s.
__global__ __launch_bounds__(256) void k_hist(const int* __restrict__ gt,
        unsigned* __restrict__ hcntT, unsigned* __restrict__ h64) {
    int tid = threadIdx.x;
    // zero the slow-path histogram: 8*65536 u32 = 131072 uint4 = HB*256
    uint4 z; z.x = z.y = z.z = z.w = 0u;
    ((uint4*)h64)[blockIdx.x * 256 + tid] = z;

    int n = blockIdx.x >> 6, b = blockIdx.x & 63;
    const int4* g4 = (const int4*)(gt + (size_t)n * HWN);
    unsigned c[16];
#pragma unroll
    for (int bin = 0; bin < 16; ++bin) c[bin] = 0u;
#pragma unroll
    for (int k = 0; k < 16; ++k) {
        int4 g = g4[b * 4096 + k * 256 + tid];
#pragma unroll
        for (int e = 0; e < 4; ++e) {
            int gv = (&g.x)[e] & 15;
#pragma unroll
            for (int bin = 0; bin < 16; ++bin)
                c[bin] += (unsigned)__popcll(__ballot(gv == bin));
        }
    }
    __shared__ unsigned sw[4][16];
    int wave = tid >> 6, lane = tid & 63;
    if (lane == 0) {
#pragma unroll
        for (int bin = 0; bin < 16; ++bin) sw[wave][bin] = c[bin];
    }
    __syncthreads();
    if (tid < 16) hcntT[tid * HB + blockIdx.x] = sw[0][tid] + sw[1][tid] + sw[2][tid] + sw[3][tid];
}

// ---------- kernel 2: main fused pass, 4 px/thread ----------
// grid: MB x 256; thread owns float4-group j across all n.
__global__ __launch_bounds__(256, 4) void k_main(const float* __restrict__ pred,
        const float* __restrict__ gdf, const int* __restrict__ gt,
        const unsigned* __restrict__ hcntT, float* __restrict__ lossBuf,
        unsigned short* __restrict__ tsumBuf, unsigned* __restrict__ h64,
        double* __restrict__ pN1, double* __restrict__ pS2, double* __restrict__ pC) {
    __shared__ unsigned sc[128];
    __shared__ float spix[128];
    __shared__ int smode[NBATCH];
    __shared__ int sAny;
    int tid = threadIdx.x;
    load_counts(hcntT, sc);
    if (tid == 0) sAny = 0;
    __syncthreads();
    if (tid < NBATCH) {
        int n = tid;
        long long sumPos = 0; int nseg = 0;
        for (int s = 1; s < 16; ++s) { sumPos += sc[n*16+s]; nseg += sc[n*16+s] ? 1 : 0; }
        long long sumNeg = sc[n*16];
        float seg_ave = (float)sumPos / (float)(nseg ? nseg : 1);
        spix[n*16] = 0.f;
        for (int s = 1; s < 16; ++s) {
            unsigned cc = sc[n*16+s];
            spix[n*16+s] = seg_ave / (float)(cc > 1u ? cc : 1u);
        }
        long long k = 3 * sumPos; if (sumNeg < k) k = sumNeg;
        int md = (k <= 0) ? 0 : ((k >= sumNeg) ? 1 : 2);
        smode[n] = md;
        if (md == 2) sAny = 1;
    }
    __syncthreads();
    bool anySlow = (sAny != 0);

    int j = blockIdx.x * 256 + tid;    // 0 .. NGRP-1
    float ts[4] = {0.f, 0.f, 0.f, 0.f};
    int   ce[4] = {0, 0, 0, 0};
    float num1f = 0.f;
#pragma unroll 4
    for (int n = 0; n < NBATCH; ++n) {
        float4 px4 = ((const float4*)pred)[(size_t)(2*n    ) * NGRP + j];
        float4 py4 = ((const float4*)pred)[(size_t)(2*n + 1) * NGRP + j];
        float4 gx4 = ((const float4*)gdf )[(size_t)(2*n    ) * NGRP + j];
        float4 gy4 = ((const float4*)gdf )[(size_t)(2*n + 1) * NGRP + j];
        int4   g4  = ((const int4*)  gt  )[(size_t)n * NGRP + j];
        int m = smode[n];
        float4 lossv;
#pragma unroll
        for (int e = 0; e < 4; ++e) {
            float px = (&px4.x)[e], py = (&py4.x)[e];
            float gx = (&gx4.x)[e], gy = (&gy4.x)[e];
            int   gv = (&g4.x)[e] & 15;
            float dx = px - gx, dy = py - gy;
            float ang = polar01(gx, gy) - polar01(px, py);
            float t = dx*dx + dy*dy + ang*ang;
            ts[e] += t;
            num1f += t * spix[n*16 + gv];
            if (m == 1) {
                ce[e] += (gv == 0 && t != 0.f) ? 1 : 0;
            } else if (m == 2) {
                float lv = (gv == 0) ? t : 0.f;
                (&lossv.x)[e] = lv;
                unsigned u = __float_as_uint(lv);
                unsigned* hh = h64 + (size_t)(blockIdx.x & 7) * 65536;
                if (u) atomicAdd(&hh[u >> 16], 1u);
            }
        }
        if (m == 2) ((float4*)lossBuf)[(size_t)n * NGRP + j] = lossv;
    }
    if (anySlow) {
        // tsum -> bf16 (RNE) for the slow-path re-scan
        ushort4 tz;
#pragma unroll
        for (int e = 0; e < 4; ++e) {
            unsigned u = __float_as_uint(ts[e]);
            (&tz.x)[e] = (unsigned short)((u + 0x7FFFu + ((u >> 16) & 1u)) >> 16);
        }
        ((ushort4*)tsumBuf)[j] = tz;
    }
    float spec2 = 0.f, cntS = 0.f;
#pragma unroll
    for (int e = 0; e < 4; ++e) { spec2 += ts[e] * (float)ce[e]; cntS += (float)ce[e]; }
    double a = (double)num1f, b = (double)spec2, c = (double)cntS;
    block_reduce3(a, b, c);
    if (tid == 0) { pN1[blockIdx.x] = a; pS2[blockIdx.x] = b; pC[blockIdx.x] = c; }
}

// ---------- kernel 3: single-block tail: combine + slow-path select + result ----------
__global__ __launch_bounds__(256) void k_tail(const unsigned* __restrict__ hcntT,
        const unsigned* __restrict__ h64, const float* __restrict__ lossBuf,
        const unsigned short* __restrict__ tsumBuf, const double* __restrict__ pN1,
        const double* __restrict__ pS2, const double* __restrict__ pC,
        float* __restrict__ out) {
    __shared__ unsigned sc[128];
    __shared__ double swsum[NBATCH];
    __shared__ int smode[NBATCH];
    __shared__ long long skv[NBATCH];
    __shared__ unsigned part[256];
    __shared__ unsigned fine[256];
    __shared__ unsigned scoarse[2];   // [0]=coarse bucket, [1]=cumAbove
    __shared__ double racc[2];
    int tid = threadIdx.x;
    load_counts(hcntT, sc);
    __syncthreads();
    if (tid < NBATCH) {
        int n = tid;
        long long sumPos = 0; int nseg = 0;
        for (int s = 1; s < 16; ++s) { sumPos += sc[n*16+s]; nseg += sc[n*16+s] ? 1 : 0; }
        long long sumNeg = sc[n*16];
        float seg_ave = (float)sumPos / (float)(nseg ? nseg : 1);
        double ws = 0.0;
        for (int s = 1; s < 16; ++s) {
            unsigned cc = sc[n*16+s];
            float pv = seg_ave / (float)(cc > 1u ? cc : 1u);
            ws += (double)pv * (double)cc;
        }
        long long k = 3 * sumPos; if (sumNeg < k) k = sumNeg;
        skv[n] = k;
        smode[n] = (k <= 0) ? 0 : ((k >= sumNeg) ? 1 : 2);
        swsum[n] = ws;
    }
    __syncthreads();

    // combine k_main partials
    double a = 0, b = 0, c = 0;
    for (int i = tid; i < MB; i += 256) { a += pN1[i]; b += pS2[i]; c += pC[i]; }
    block_reduce3(a, b, c);
    if (tid == 0) { racc[0] = b; racc[1] = c; }   // num2, msum (fast part)
    __syncthreads();

    // slow samples: find 16-bit-bucket threshold, then stream lossBuf
    for (int n = 0; n < NBATCH; ++n) {
        if (smode[n] != 2) continue;
        unsigned loc = 0;
        int base = tid * 256;
        for (int i = 0; i < 256; ++i) {
            unsigned s = 0;
#pragma unroll
            for (int r = 0; r < 8; ++r) s += h64[r * 65536 + base + i];
            loc += s;
        }
        part[tid] = loc;
        __syncthreads();
        if (tid == 0) {
            long long nnz = 0;
            for (int i = 0; i < 256; ++i) nnz += part[i];
            long long k = skv[n];
            if (k >= nnz) { scoarse[0] = 0xFFFFFFFFu; }   // keep all nonzero (T=0)
            else {
                unsigned cum = 0; int cc2 = 0;
                for (int i = 255; i >= 0; --i) {
                    if ((long long)cum + part[i] >= k) { cc2 = i; break; }
                    cum += part[i];
                }
                scoarse[0] = (unsigned)cc2; scoarse[1] = cum;
            }
        }
        __syncthreads();
        unsigned T = 0u;
        if (scoarse[0] != 0xFFFFFFFFu) {
            unsigned cc2 = scoarse[0];
            unsigned s = 0;
#pragma unroll
            for (int r = 0; r < 8; ++r) s += h64[r * 65536 + cc2 * 256 + tid];
            fine[tid] = s;
            __syncthreads();
            if (tid == 0) {
                long long k = skv[n];
                unsigned cum = scoarse[1]; int bb = 0;
                for (int i = 255; i >= 0; --i) {
                    if ((long long)cum + fine[i] >= k) { bb = i; break; }
                    cum += fine[i];
                }
                scoarse[0] = (scoarse[0] << 8) | (unsigned)bb;   // 16-bit bucket
            }
            __syncthreads();
            T = scoarse[0] << 16;
            __syncthreads();
        }
        // stream this sample's loss + tsum
        double acc = 0.0, cnt = 0.0;
        const float2* lp = (const float2*)(lossBuf + (size_t)n * HWN);
        const ushort2* tp = (const ushort2*)tsumBuf;
        for (int i = tid; i < NPAIR; i += 256) {
            float2 lv = lp[i];
            ushort2 tz = tp[i];
            unsigned u0 = __float_as_uint(lv.x), u1 = __float_as_uint(lv.y);
            if (u0 != 0u && u0 >= T) { acc += (double)__uint_as_float(((unsigned)tz.x) << 16); cnt += 1.0; }
            if (u1 != 0u && u1 >= T) { acc += (double)__uint_as_float(((unsigned)tz.y) << 16); cnt += 1.0; }
        }
        block_reduce2(acc, cnt);
        if (tid == 0) { racc[0] += acc; racc[1] += cnt; }
        __syncthreads();
    }

    if (tid == 0) {
        double wsum = 0.0;
        for (int n = 0; n < NBATCH; ++n) wsum += swsum[n];
        double num = (double)NBATCH * a + racc[0];
        double den = (double)NBATCH * (wsum + racc[1]);
        out[0] = (float)(num / (double)NBATCH / 2.0 / den);
    }
}

// ---------- launcher: 3 dispatch nodes, no memset ----------

extern "C" void kernel_launch(void* const* d_in, const int* in_sizes, int n_in,
                              void* d_out, int out_size, void* d_ws, size_t ws_size,
                              hipStream_t stream) {
    const float* pred = (const float*)d_in[0];
    const float* gdf  = (const float*)d_in[1];
    const int*   gt   = (const int*)d_in[2];
    float* out = (float*)d_out;

    char* W = (char*)d_ws;
    float* lossBuf = (float*)W;                                   // 32 MiB (slow path only)
    unsigned short* tsumBuf = (unsigned short*)(W + 33554432);    // 2 MiB (slow path only)
    unsigned* h64   = (unsigned*)(W + 35651584);                  // 8*65536*4 = 2 MiB
    unsigned* hcntT = (unsigned*)(W + 37748736);                  // 16*512*4 = 32 KiB
    double*   pN1   = (double*)(W + 37781504);                    // MB doubles
    double*   pS2   = pN1 + MB;
    double*   pC    = pS2 + MB;

    size_t need = 37781504 + (size_t)3 * MB * 8;
    if (ws_size < need) return;

    k_hist<<<HB, 256, 0, stream>>>(gt, hcntT, h64);
    k_main<<<MB, 256, 0, stream>>>(pred, gdf, gt, hcntT, lossBuf, tsumBuf, h64, pN1, pS2, pC);
    k_tail<<<1, 256, 0, stream>>>(hcntT, h64, lossBuf, tsumBuf, pN1, pS2, pC, out);
}